// Round 21
// baseline (1739.184 us; speedup 1.0000x reference)
//
#include <hip/hip_runtime.h>
#include <math.h>

#define NSAMP 32768      // time-domain samples
#define MH    16384      // half-size complex FFT length (= 4^7)
#define LFREQ 32770      // rfft concat(re,im) length = 2*(NSAMP/2+1)
#define NRE   16385      // number of rfft bins
#define NB    64         // batches
#define NA    512        // atoms
#define NITER 64
#define RSTR  32772      // padded row stride for fp32 res0/rec in ws

#define KPS    33280     // bf16 row stride (zero-padded past LFREQ)
#define NSL    64        // k-slices for MFMA dots (512 k each; k=32768 is a rank-1 term)
#define BN2    128       // atoms per dots block
#define NCH    4097      // ceil(LFREQ/8) 8-float chunks per row

typedef __attribute__((ext_vector_type(8))) short bf16x8;
typedef __attribute__((ext_vector_type(8))) unsigned short u16x8;
typedef __attribute__((ext_vector_type(4))) float f32x4;

// base-4 digit reversal of a 14-bit index (7 digits)
__device__ __forceinline__ int rev4_14(int v) {
  unsigned r = __brev((unsigned)v) >> 18;
  r = ((r & 0x1555u) << 1) | ((r >> 1) & 0x1555u);
  return (int)r;
}

__device__ __forceinline__ unsigned short f2bf(float f) {
  unsigned u = __float_as_uint(f);
  u = (u + 0x7fffu + ((u >> 16) & 1u)) >> 16;   // round-to-nearest-even
  return (unsigned short)u;
}
__device__ __forceinline__ float bf2f(unsigned short h) {
  return __uint_as_float(((unsigned)h) << 16);
}

__device__ __forceinline__ float2 cmul(float2 a, float2 b) {
  return make_float2(a.x * b.x - a.y * b.y, a.x * b.y + a.y * b.x);
}

// ---------------- fat prologue: blocks 0..63 = forward rfft of batch b;
//                  blocks 64..575 = atom (bid-64): norm + bf16 hi/lo convert ----------------
__global__ __launch_bounds__(1024) void prologue_kernel(const float* __restrict__ x,
                                                        float* __restrict__ res0,
                                                        unsigned short* __restrict__ resH,
                                                        unsigned short* __restrict__ resL,
                                                        const float* __restrict__ atoms,
                                                        float* __restrict__ rnorm,
                                                        float* __restrict__ anv,
                                                        unsigned short* __restrict__ anH,
                                                        unsigned short* __restrict__ anL) {
  extern __shared__ float2 s[];   // 128 KB
  const int t = threadIdx.x;
  if (blockIdx.x >= 64) {
    // ---- atom path: norm + convert (row re-read is L2-hot) ----
    const int a = blockIdx.x - 64;
    float* red = (float*)s;
    const float* row = atoms + (size_t)a * LFREQ;
    const float2* row2 = (const float2*)row;
    float ss = 0.f;
    for (int i = t; i < LFREQ / 2; i += 1024) {   // 16385 float2 exactly
      const float2 v = row2[i];
      ss += v.x * v.x + v.y * v.y;
    }
    red[t] = ss; __syncthreads();
    for (int st = 512; st > 0; st >>= 1) {
      if (t < st) red[t] += red[t + st];
      __syncthreads();
    }
    const float rn = 1.0f / sqrtf(red[0]);
    if (t == 0) {
      rnorm[a] = rn;
      anv[a] = atoms[(size_t)a * LFREQ + 32768] * rn;
    }
    unsigned short* hrow = anH + (size_t)a * KPS;
    unsigned short* lrow = anL + (size_t)a * KPS;
    for (int c = t; c < KPS / 8; c += 1024) {
      const int k0 = c * 8;
      float v[8];
      if (k0 + 8 <= LFREQ) {
        #pragma unroll
        for (int e = 0; e < 4; ++e) {
          const float2 p = *(const float2*)(row + k0 + 2 * e);
          v[2 * e] = p.x; v[2 * e + 1] = p.y;
        }
      } else {
        #pragma unroll
        for (int e = 0; e < 8; ++e) v[e] = (k0 + e < LFREQ) ? row[k0 + e] : 0.f;
      }
      u16x8 hv, lv;
      #pragma unroll
      for (int e = 0; e < 8; ++e) {
        const float sv = v[e] * rn;
        const unsigned short h = f2bf(sv);
        hv[e] = h;
        lv[e] = f2bf(sv - bf2f(h));
      }
      *(u16x8*)(hrow + k0) = hv;
      *(u16x8*)(lrow + k0) = lv;
    }
    return;
  }
  // ---- FFT path ----
  const int b = blockIdx.x;
  const float2* xrow = (const float2*)(x + (size_t)b * NSAMP);
  for (int m = t; m < MH; m += 1024) s[m] = xrow[rev4_14(m)];
  __syncthreads();
  for (int st = 0; st < 7; ++st) {
    const int q = 1 << (2 * st);
    const float fac = 6.283185307179586f / (float)(4 * q);
    for (int j = t; j < MH / 4; j += 1024) {
      const int blk = j >> (2 * st), pos = j & (q - 1);
      const int i0 = (blk << (2 * st + 2)) + pos;
      float sn, cs; __sincosf(fac * (float)pos, &sn, &cs);
      const float2 w1 = make_float2(cs, -sn);
      const float2 w2 = cmul(w1, w1);
      const float2 w3 = cmul(w2, w1);
      const float2 a0 = s[i0], a1 = s[i0 + q], a2 = s[i0 + 2 * q], a3 = s[i0 + 3 * q];
      const float2 x1 = cmul(w1, a1), x2 = cmul(w2, a2), x3 = cmul(w3, a3);
      const float2 s0 = make_float2(a0.x + x2.x, a0.y + x2.y);
      const float2 s1 = make_float2(a0.x - x2.x, a0.y - x2.y);
      const float2 t0 = make_float2(x1.x + x3.x, x1.y + x3.y);
      const float2 t1 = make_float2(x1.x - x3.x, x1.y - x3.y);
      s[i0]         = make_float2(s0.x + t0.x, s0.y + t0.y);
      s[i0 + q]     = make_float2(s1.x + t1.y, s1.y - t1.x);
      s[i0 + 2 * q] = make_float2(s0.x - t0.x, s0.y - t0.y);
      s[i0 + 3 * q] = make_float2(s1.x - t1.y, s1.y + t1.x);
    }
    __syncthreads();
  }
  float* rr = res0 + (size_t)b * RSTR;
  unsigned short* hrow = resH + (size_t)b * KPS;
  unsigned short* lrow = resL + (size_t)b * KPS;
  const float fac2 = 6.283185307179586f / (float)NSAMP;
  for (int k = t; k < MH; k += 1024) {
    if (k == 0) {
      const float2 z0 = s[0];
      const float dc = z0.x + z0.y, ny = z0.x - z0.y;
      rr[0] = dc;   rr[NRE] = 0.f;
      rr[MH] = ny;  rr[NRE + MH] = 0.f;
      unsigned short h;
      h = f2bf(dc); hrow[0] = h;  lrow[0] = f2bf(dc - bf2f(h));
      h = f2bf(ny); hrow[MH] = h; lrow[MH] = f2bf(ny - bf2f(h));
      hrow[NRE] = 0; lrow[NRE] = 0;
      hrow[NRE + MH] = 0; lrow[NRE + MH] = 0;
    } else {
      const float2 zk = s[k], zm = s[MH - k];
      const float xer = 0.5f * (zk.x + zm.x), xei = 0.5f * (zk.y - zm.y);
      const float p = 0.5f * (zk.y + zm.y);
      const float q = -0.5f * (zk.x - zm.x);
      float sn, cs; __sincosf(fac2 * (float)k, &sn, &cs);
      const float vr = xer + cs * p + sn * q;
      const float vi = xei + cs * q - sn * p;
      rr[k]       = vr;
      rr[NRE + k] = vi;
      unsigned short h;
      h = f2bf(vr); hrow[k] = h;       lrow[k] = f2bf(vr - bf2f(h));
      h = f2bf(vi); hrow[NRE + k] = h; lrow[NRE + k] = f2bf(vi - bf2f(h));
    }
  }
}

// ---------------- inverse rfft: rec[b][32770] -> out[b][32768] ----------------
__global__ __launch_bounds__(1024) void fft_inv_kernel(const float* __restrict__ rec,
                                                       float* __restrict__ out) {
  extern __shared__ float2 s[];
  const int b = blockIdx.x, t = threadIdx.x;
  const float* rr = rec + (size_t)b * RSTR;
  const float fac2 = 6.283185307179586f / (float)NSAMP;
  for (int m = t; m < MH; m += 1024) {
    const int k = rev4_14(m);
    float2 z;
    if (k == 0) {
      const float a0 = rr[0], aM = rr[MH];
      z = make_float2(0.5f * (a0 + aM), 0.5f * (a0 - aM));
    } else {
      const float xr_ = rr[k],       xi_ = rr[NRE + k];
      const float mr  = rr[MH - k],  mi  = rr[NRE + MH - k];
      const float xer = 0.5f * (xr_ + mr), xei = 0.5f * (xi_ - mi);
      const float er  = 0.5f * (xr_ - mr), ei  = 0.5f * (xi_ + mi);
      float sn, cs; __sincosf(fac2 * (float)k, &sn, &cs);
      const float xor_ = cs * er - sn * ei;
      const float xoi  = cs * ei + sn * er;
      z = make_float2(xer - xoi, xei + xor_);
    }
    s[m] = z;
  }
  __syncthreads();
  for (int st = 0; st < 7; ++st) {
    const int q = 1 << (2 * st);
    const float fac = 6.283185307179586f / (float)(4 * q);
    for (int j = t; j < MH / 4; j += 1024) {
      const int blk = j >> (2 * st), pos = j & (q - 1);
      const int i0 = (blk << (2 * st + 2)) + pos;
      float sn, cs; __sincosf(fac * (float)pos, &sn, &cs);
      const float2 w1 = make_float2(cs, sn);
      const float2 w2 = cmul(w1, w1);
      const float2 w3 = cmul(w2, w1);
      const float2 a0 = s[i0], a1 = s[i0 + q], a2 = s[i0 + 2 * q], a3 = s[i0 + 3 * q];
      const float2 x1 = cmul(w1, a1), x2 = cmul(w2, a2), x3 = cmul(w3, a3);
      const float2 s0 = make_float2(a0.x + x2.x, a0.y + x2.y);
      const float2 s1 = make_float2(a0.x - x2.x, a0.y - x2.y);
      const float2 t0 = make_float2(x1.x + x3.x, x1.y + x3.y);
      const float2 t1 = make_float2(x1.x - x3.x, x1.y - x3.y);
      s[i0]         = make_float2(s0.x + t0.x, s0.y + t0.y);
      s[i0 + q]     = make_float2(s1.x - t1.y, s1.y + t1.x);
      s[i0 + 2 * q] = make_float2(s0.x - t0.x, s0.y - t0.y);
      s[i0 + 3 * q] = make_float2(s1.x + t1.y, s1.y - t1.x);
    }
    __syncthreads();
  }
  const float inv = 1.0f / (float)MH;
  float2* orow = (float2*)(out + (size_t)b * NSAMP);
  for (int m = t; m < MH; m += 1024) {
    const float2 z = s[m];
    orow[m] = make_float2(z.x * inv, z.y * inv);
  }
}

// ---------------- dots: 64 batches x 128 atoms per block, split-bf16 MFMA, 3-buffer ----
// 1024 threads / 16 waves: wave w owns 16 batches (bh=w>>2) x 32 atoms (aq=w&3).
// partials[b][s][a] = sum_{k in slice s} res[b][k] * an[a][k]   (k < 32768 only)
// LDS per buf (48 KB): AH 8K | AL 8K | BH 16K | BL 16K, in 1KB fragment units.
__global__ __launch_bounds__(1024) void dots_mfma_kernel(const unsigned short* __restrict__ resH,
                                                         const unsigned short* __restrict__ resL,
                                                         const unsigned short* __restrict__ anH,
                                                         const unsigned short* __restrict__ anL,
                                                         float* __restrict__ partials) {
  __shared__ char smem[147456];  // 3 x 48KB
  const int slice = blockIdx.x;  // 0..NSL-1, K = 512 per block, chunks of 64
  const int atile = blockIdx.y;  // 0..3, 128 atoms each
  const int t = threadIdx.x;
  const int w = t >> 6, l = t & 63;
  const int bh = w >> 2, aq = w & 3;        // wave: 16 batches x 32 atoms
  const int kc0 = slice * 512;

  f32x4 acc00 = {0.f,0.f,0.f,0.f}, acc01 = acc00;

  // staging: 48 units of 1KB per chunk; wave w stages units w*3 .. w*3+2
#define STAGE(cc, bb)                                                                     \
  {                                                                                       \
    const int kc = kc0 + (cc) * 64;                                                       \
    _Pragma("unroll")                                                                     \
    for (int j = 0; j < 3; ++j) {                                                         \
      const int u = w * 3 + j;                                                            \
      const unsigned short* gt = (u < 8) ? resH : (u < 16) ? resL : (u < 32) ? anH : anL; \
      const int base = (u < 8) ? 0 : (u < 16) ? 8192 : (u < 32) ? 16384 : 32768;          \
      const int usec = u - ((u < 8) ? 0 : (u < 16) ? 8 : (u < 32) ? 16 : 32);             \
      const int row0 = (u < 16) ? 0 : atile * BN2;                                        \
      const int rt = usec >> 1, kk = usec & 1;                                            \
      const unsigned short* g = gt + (size_t)(row0 + rt * 16 + (l & 15)) * KPS            \
                                + kc + kk * 32 + (l >> 4) * 8;                            \
      char* d = smem + (bb) * 49152 + base + usec * 1024 + l * 16;                        \
      __builtin_amdgcn_global_load_lds((const __attribute__((address_space(1))) void*)g,  \
                                       (__attribute__((address_space(3))) void*)d,        \
                                       16, 0, 0);                                        \
    }                                                                                     \
  }

#define COMPUTE(bb)                                                                      \
  {                                                                                       \
    const char* base = smem + (bb) * 49152;                                               \
    _Pragma("unroll")                                                                     \
    for (int kk = 0; kk < 2; ++kk) {                                                      \
      const bf16x8 aH0 = *(const bf16x8*)(base + (bh * 2 + kk) * 1024 + l * 16);          \
      const bf16x8 aL0 = *(const bf16x8*)(base + 8192 + (bh * 2 + kk) * 1024 + l * 16);   \
      const bf16x8 bH0 = *(const bf16x8*)(base + 16384 + ((aq * 2 + 0) * 2 + kk) * 1024 + l * 16);\
      const bf16x8 bH1 = *(const bf16x8*)(base + 16384 + ((aq * 2 + 1) * 2 + kk) * 1024 + l * 16);\
      const bf16x8 bL0 = *(const bf16x8*)(base + 32768 + ((aq * 2 + 0) * 2 + kk) * 1024 + l * 16);\
      const bf16x8 bL1 = *(const bf16x8*)(base + 32768 + ((aq * 2 + 1) * 2 + kk) * 1024 + l * 16);\
      acc00 = __builtin_amdgcn_mfma_f32_16x16x32_bf16(aH0, bH0, acc00, 0, 0, 0);          \
      acc01 = __builtin_amdgcn_mfma_f32_16x16x32_bf16(aH0, bH1, acc01, 0, 0, 0);          \
      acc00 = __builtin_amdgcn_mfma_f32_16x16x32_bf16(aH0, bL0, acc00, 0, 0, 0);          \
      acc01 = __builtin_amdgcn_mfma_f32_16x16x32_bf16(aH0, bL1, acc01, 0, 0, 0);          \
      acc00 = __builtin_amdgcn_mfma_f32_16x16x32_bf16(aL0, bH0, acc00, 0, 0, 0);          \
      acc01 = __builtin_amdgcn_mfma_f32_16x16x32_bf16(aL0, bH1, acc01, 0, 0, 0);          \
    }                                                                                     \
  }

  STAGE(0, 0);
  STAGE(1, 1);
  #pragma unroll
  for (int c = 0; c < 8; ++c) {
    const int bf = c - (c / 3) * 3;   // c % 3
    if (c < 7) {
      asm volatile("s_waitcnt vmcnt(3)" ::: "memory");   // own chunk-c loads retired
    } else {
      asm volatile("s_waitcnt vmcnt(0)" ::: "memory");
    }
    __builtin_amdgcn_s_barrier();            // all waves' chunk-c loads landed
    __builtin_amdgcn_sched_barrier(0);
    COMPUTE(bf);
    __builtin_amdgcn_sched_barrier(0);
    if (c < 6) {
      const int nb = c + 2;
      STAGE(nb, nb - (nb / 3) * 3);          // buf (c+2)%3 — last read finished pre-barrier
    }
  }
#undef STAGE
#undef COMPUTE

  // D layout: row=(lane>>4)*4+e (batch), col=lane&15 (atom); partials [b][NSL][a]
  const int acol = atile * BN2 + aq * 32 + (l & 15);
  const size_t bstr = (size_t)NSL * NA;
  #pragma unroll
  for (int e = 0; e < 4; ++e) {
    const size_t r0 = (size_t)(bh * 16 + (l >> 4) * 4 + e);
    partials[r0 * bstr + (size_t)slice * NA + acol]      = acc00[e];
    partials[r0 * bstr + (size_t)slice * NA + acol + 16] = acc01[e];
  }
}

// ---------------- fused per-batch: argmax (single scan) + full-row update ----------------
__global__ __launch_bounds__(1024) void argmax_update_kernel(const float* __restrict__ partials,
                                                             const float* __restrict__ atoms,
                                                             const float* __restrict__ rnorm,
                                                             const float* __restrict__ anv,
                                                             unsigned short* __restrict__ resH,
                                                             unsigned short* __restrict__ resL,
                                                             const float* __restrict__ res0,
                                                             float* __restrict__ rec,
                                                             float* __restrict__ out2,
                                                             int final_out) {
  const int b = blockIdx.x;
  const int t = threadIdx.x;
  unsigned short* hrow = resH + (size_t)b * KPS;
  unsigned short* lrow = resL + (size_t)b * KPS;

  // ---- phase 1: argmax (identical summation order to R19's reduce_argmax) ----
  __shared__ float sv[1024];
  __shared__ int si[1024];
  {
    const int a = t & 511, half = t >> 9;
    const float* pb = partials + (size_t)b * NSL * NA + (size_t)half * 32 * NA;
    float d = 0.f;
    #pragma unroll 16
    for (int s = 0; s < 32; ++s) d += pb[(size_t)s * NA + a];
    sv[t] = d; __syncthreads();
    if (t < 512) {
      float dd = sv[t] + sv[t + 512];
      const float rv = bf2f(hrow[32768]) + bf2f(lrow[32768]);   // k=32768 rank-1 term
      dd = fmaf(rv, anv[t], dd);
      sv[t] = dd; si[t] = t;
    }
    __syncthreads();
    for (int st = 256; st > 0; st >>= 1) {
      if (t < st) {
        const float v2 = sv[t + st]; const int i2 = si[t + st];
        if (v2 > sv[t] || (v2 == sv[t] && i2 < si[t])) { sv[t] = v2; si[t] = i2; }
      }
      __syncthreads();
    }
  }
  const int idx = si[0];

  // ---- phase 2: full-row update with 1024 threads ----
  const float rn = rnorm[idx];
  const float* arow = atoms + (size_t)idx * LFREQ;
  const float* r0row = res0 + (size_t)b * RSTR;
  float* recrow = rec + (size_t)b * RSTR;
  float* orow = out2 + (size_t)b * LFREQ;
  for (int c = t; c < NCH; c += 1024) {
    const int k0 = c * 8;
    if (k0 + 8 <= LFREQ) {
      const u16x8 hv0 = *(const u16x8*)(hrow + k0);
      const u16x8 lv0 = *(const u16x8*)(lrow + k0);
      float av[8];
      #pragma unroll
      for (int e = 0; e < 4; ++e) {
        const float2 p = *(const float2*)(arow + k0 + 2 * e);
        av[2 * e] = p.x; av[2 * e + 1] = p.y;
      }
      float nv[8];
      u16x8 hv, lv;
      #pragma unroll
      for (int e = 0; e < 8; ++e) {
        const float r = bf2f(hv0[e]) + bf2f(lv0[e]);
        const float bx = av[e] * rn * r;
        nv[e] = r - bx;
        const unsigned short h = f2bf(nv[e]);
        hv[e] = h;
        lv[e] = f2bf(nv[e] - bf2f(h));
      }
      *(u16x8*)(hrow + k0) = hv;
      *(u16x8*)(lrow + k0) = lv;
      if (final_out) {
        #pragma unroll
        for (int e = 0; e < 2; ++e) {
          const float4 r0 = *(const float4*)(r0row + k0 + 4 * e);
          *(float4*)(orow + k0 + 4 * e) = make_float4(nv[4*e], nv[4*e+1], nv[4*e+2], nv[4*e+3]);
          *(float4*)(recrow + k0 + 4 * e) = make_float4(r0.x - nv[4*e], r0.y - nv[4*e+1],
                                                       r0.z - nv[4*e+2], r0.w - nv[4*e+3]);
        }
      }
    } else {
      for (int e = 0; e < 8; ++e) {
        const int k = k0 + e;
        if (k < LFREQ) {
          const float r = bf2f(hrow[k]) + bf2f(lrow[k]);
          const float bx = arow[k] * rn * r;
          const float nx = r - bx;
          const unsigned short h = f2bf(nx);
          hrow[k] = h;
          lrow[k] = f2bf(nx - bf2f(h));
          if (final_out) {
            orow[k] = nx;
            recrow[k] = r0row[k] - nx;
          }
        }
      }
    }
  }
}

extern "C" void kernel_launch(void* const* d_in, const int* in_sizes, int n_in,
                              void* d_out, int out_size, void* d_ws, size_t ws_size,
                              hipStream_t stream) {
  const float* x = (const float*)d_in[0];      // (64,1,32768)
  const float* atoms = (const float*)d_in[1];  // (1,512,32770)
  float* out = (float*)d_out;

  float* res0 = (float*)d_ws;                            // 64*32772 f32 (initial rfft)
  float* rec = res0 + (size_t)NB * RSTR;                 // 64*32772 f32 (final only)
  float* rnorm = rec + (size_t)NB * RSTR;                // 512
  float* anv = rnorm + NA;                               // 512
  float* partials = anv + NA;                            // 64*64*512 f32  [b][s][a]
  unsigned short* resH = (unsigned short*)(partials + (size_t)NB * NSL * NA);
  unsigned short* resL = resH + (size_t)NB * KPS;
  unsigned short* anH  = resL + (size_t)NB * KPS;
  unsigned short* anL  = anH + (size_t)NA * KPS;

  prologue_kernel<<<64 + NA, 1024, MH * sizeof(float2), stream>>>(x, res0, resH, resL,
                                                                  atoms, rnorm, anv,
                                                                  anH, anL);

  float* res_out = out + (size_t)NB * NSAMP;
  for (int it = 0; it < NITER; ++it) {
    dots_mfma_kernel<<<dim3(NSL, 4), 1024, 0, stream>>>(resH, resL, anH, anL, partials);
    argmax_update_kernel<<<NB, 1024, 0, stream>>>(partials, atoms, rnorm, anv,
                                                  resH, resL, res0, rec, res_out,
                                                  (it == NITER - 1) ? 1 : 0);
  }

  fft_inv_kernel<<<NB, 1024, MH * sizeof(float2), stream>>>(rec, out);
}

// Round 22
// 1712.115 us; speedup vs baseline: 1.0158x; 1.0158x over previous
//
#include <hip/hip_runtime.h>
#include <math.h>

#define NSAMP 32768      // time-domain samples
#define MH    16384      // half-size complex FFT length (= 4^7)
#define LFREQ 32770      // rfft concat(re,im) length = 2*(NSAMP/2+1)
#define NRE   16385      // number of rfft bins
#define NB    64         // batches
#define NA    512        // atoms
#define NITER 64
#define RSTR  32772      // padded row stride for fp32 res0/rec in ws

#define KPS    33280     // bf16 row stride (zero-padded past LFREQ)
#define NSL    64        // k-slices for MFMA dots (512 k each; k=32768 is a rank-1 term)
#define BN2    128       // atoms per dots block
#define NCH    4097      // ceil(LFREQ/8) 8-float chunks per row

typedef __attribute__((ext_vector_type(8))) short bf16x8;
typedef __attribute__((ext_vector_type(8))) unsigned short u16x8;
typedef __attribute__((ext_vector_type(4))) float f32x4;

// base-4 digit reversal of a 14-bit index (7 digits)
__device__ __forceinline__ int rev4_14(int v) {
  unsigned r = __brev((unsigned)v) >> 18;
  r = ((r & 0x1555u) << 1) | ((r >> 1) & 0x1555u);
  return (int)r;
}

__device__ __forceinline__ unsigned short f2bf(float f) {
  unsigned u = __float_as_uint(f);
  u = (u + 0x7fffu + ((u >> 16) & 1u)) >> 16;   // round-to-nearest-even
  return (unsigned short)u;
}
__device__ __forceinline__ float bf2f(unsigned short h) {
  return __uint_as_float(((unsigned)h) << 16);
}

__device__ __forceinline__ float2 cmul(float2 a, float2 b) {
  return make_float2(a.x * b.x - a.y * b.y, a.x * b.y + a.y * b.x);
}

// ---------------- fat prologue: blocks 0..63 = forward rfft of batch b;
//                  blocks 64..575 = atom (bid-64): norm + bf16 hi/lo convert ----------------
__global__ __launch_bounds__(1024) void prologue_kernel(const float* __restrict__ x,
                                                        float* __restrict__ res0,
                                                        unsigned short* __restrict__ resH,
                                                        unsigned short* __restrict__ resL,
                                                        const float* __restrict__ atoms,
                                                        float* __restrict__ rnorm,
                                                        float* __restrict__ anv,
                                                        unsigned short* __restrict__ anH,
                                                        unsigned short* __restrict__ anL) {
  extern __shared__ float2 s[];   // 128 KB
  const int t = threadIdx.x;
  if (blockIdx.x >= 64) {
    // ---- atom path: norm + convert (row re-read is L2-hot) ----
    const int a = blockIdx.x - 64;
    float* red = (float*)s;
    const float* row = atoms + (size_t)a * LFREQ;
    const float2* row2 = (const float2*)row;
    float ss = 0.f;
    for (int i = t; i < LFREQ / 2; i += 1024) {   // 16385 float2 exactly
      const float2 v = row2[i];
      ss += v.x * v.x + v.y * v.y;
    }
    red[t] = ss; __syncthreads();
    for (int st = 512; st > 0; st >>= 1) {
      if (t < st) red[t] += red[t + st];
      __syncthreads();
    }
    const float rn = 1.0f / sqrtf(red[0]);
    if (t == 0) {
      rnorm[a] = rn;
      anv[a] = atoms[(size_t)a * LFREQ + 32768] * rn;
    }
    unsigned short* hrow = anH + (size_t)a * KPS;
    unsigned short* lrow = anL + (size_t)a * KPS;
    for (int c = t; c < KPS / 8; c += 1024) {
      const int k0 = c * 8;
      float v[8];
      if (k0 + 8 <= LFREQ) {
        #pragma unroll
        for (int e = 0; e < 4; ++e) {
          const float2 p = *(const float2*)(row + k0 + 2 * e);
          v[2 * e] = p.x; v[2 * e + 1] = p.y;
        }
      } else {
        #pragma unroll
        for (int e = 0; e < 8; ++e) v[e] = (k0 + e < LFREQ) ? row[k0 + e] : 0.f;
      }
      u16x8 hv, lv;
      #pragma unroll
      for (int e = 0; e < 8; ++e) {
        const float sv = v[e] * rn;
        const unsigned short h = f2bf(sv);
        hv[e] = h;
        lv[e] = f2bf(sv - bf2f(h));
      }
      *(u16x8*)(hrow + k0) = hv;
      *(u16x8*)(lrow + k0) = lv;
    }
    return;
  }
  // ---- FFT path ----
  const int b = blockIdx.x;
  const float2* xrow = (const float2*)(x + (size_t)b * NSAMP);
  for (int m = t; m < MH; m += 1024) s[m] = xrow[rev4_14(m)];
  __syncthreads();
  for (int st = 0; st < 7; ++st) {
    const int q = 1 << (2 * st);
    const float fac = 6.283185307179586f / (float)(4 * q);
    for (int j = t; j < MH / 4; j += 1024) {
      const int blk = j >> (2 * st), pos = j & (q - 1);
      const int i0 = (blk << (2 * st + 2)) + pos;
      float sn, cs; __sincosf(fac * (float)pos, &sn, &cs);
      const float2 w1 = make_float2(cs, -sn);
      const float2 w2 = cmul(w1, w1);
      const float2 w3 = cmul(w2, w1);
      const float2 a0 = s[i0], a1 = s[i0 + q], a2 = s[i0 + 2 * q], a3 = s[i0 + 3 * q];
      const float2 x1 = cmul(w1, a1), x2 = cmul(w2, a2), x3 = cmul(w3, a3);
      const float2 s0 = make_float2(a0.x + x2.x, a0.y + x2.y);
      const float2 s1 = make_float2(a0.x - x2.x, a0.y - x2.y);
      const float2 t0 = make_float2(x1.x + x3.x, x1.y + x3.y);
      const float2 t1 = make_float2(x1.x - x3.x, x1.y - x3.y);
      s[i0]         = make_float2(s0.x + t0.x, s0.y + t0.y);
      s[i0 + q]     = make_float2(s1.x + t1.y, s1.y - t1.x);
      s[i0 + 2 * q] = make_float2(s0.x - t0.x, s0.y - t0.y);
      s[i0 + 3 * q] = make_float2(s1.x - t1.y, s1.y + t1.x);
    }
    __syncthreads();
  }
  float* rr = res0 + (size_t)b * RSTR;
  unsigned short* hrow = resH + (size_t)b * KPS;
  unsigned short* lrow = resL + (size_t)b * KPS;
  const float fac2 = 6.283185307179586f / (float)NSAMP;
  for (int k = t; k < MH; k += 1024) {
    if (k == 0) {
      const float2 z0 = s[0];
      const float dc = z0.x + z0.y, ny = z0.x - z0.y;
      rr[0] = dc;   rr[NRE] = 0.f;
      rr[MH] = ny;  rr[NRE + MH] = 0.f;
      unsigned short h;
      h = f2bf(dc); hrow[0] = h;  lrow[0] = f2bf(dc - bf2f(h));
      h = f2bf(ny); hrow[MH] = h; lrow[MH] = f2bf(ny - bf2f(h));
      hrow[NRE] = 0; lrow[NRE] = 0;
      hrow[NRE + MH] = 0; lrow[NRE + MH] = 0;
    } else {
      const float2 zk = s[k], zm = s[MH - k];
      const float xer = 0.5f * (zk.x + zm.x), xei = 0.5f * (zk.y - zm.y);
      const float p = 0.5f * (zk.y + zm.y);
      const float q = -0.5f * (zk.x - zm.x);
      float sn, cs; __sincosf(fac2 * (float)k, &sn, &cs);
      const float vr = xer + cs * p + sn * q;
      const float vi = xei + cs * q - sn * p;
      rr[k]       = vr;
      rr[NRE + k] = vi;
      unsigned short h;
      h = f2bf(vr); hrow[k] = h;       lrow[k] = f2bf(vr - bf2f(h));
      h = f2bf(vi); hrow[NRE + k] = h; lrow[NRE + k] = f2bf(vi - bf2f(h));
    }
  }
}

// ---------------- inverse rfft: rec[b][32770] -> out[b][32768] ----------------
__global__ __launch_bounds__(1024) void fft_inv_kernel(const float* __restrict__ rec,
                                                       float* __restrict__ out) {
  extern __shared__ float2 s[];
  const int b = blockIdx.x, t = threadIdx.x;
  const float* rr = rec + (size_t)b * RSTR;
  const float fac2 = 6.283185307179586f / (float)NSAMP;
  for (int m = t; m < MH; m += 1024) {
    const int k = rev4_14(m);
    float2 z;
    if (k == 0) {
      const float a0 = rr[0], aM = rr[MH];
      z = make_float2(0.5f * (a0 + aM), 0.5f * (a0 - aM));
    } else {
      const float xr_ = rr[k],       xi_ = rr[NRE + k];
      const float mr  = rr[MH - k],  mi  = rr[NRE + MH - k];
      const float xer = 0.5f * (xr_ + mr), xei = 0.5f * (xi_ - mi);
      const float er  = 0.5f * (xr_ - mr), ei  = 0.5f * (xi_ + mi);
      float sn, cs; __sincosf(fac2 * (float)k, &sn, &cs);
      const float xor_ = cs * er - sn * ei;
      const float xoi  = cs * ei + sn * er;
      z = make_float2(xer - xoi, xei + xor_);
    }
    s[m] = z;
  }
  __syncthreads();
  for (int st = 0; st < 7; ++st) {
    const int q = 1 << (2 * st);
    const float fac = 6.283185307179586f / (float)(4 * q);
    for (int j = t; j < MH / 4; j += 1024) {
      const int blk = j >> (2 * st), pos = j & (q - 1);
      const int i0 = (blk << (2 * st + 2)) + pos;
      float sn, cs; __sincosf(fac * (float)pos, &sn, &cs);
      const float2 w1 = make_float2(cs, sn);
      const float2 w2 = cmul(w1, w1);
      const float2 w3 = cmul(w2, w1);
      const float2 a0 = s[i0], a1 = s[i0 + q], a2 = s[i0 + 2 * q], a3 = s[i0 + 3 * q];
      const float2 x1 = cmul(w1, a1), x2 = cmul(w2, a2), x3 = cmul(w3, a3);
      const float2 s0 = make_float2(a0.x + x2.x, a0.y + x2.y);
      const float2 s1 = make_float2(a0.x - x2.x, a0.y - x2.y);
      const float2 t0 = make_float2(x1.x + x3.x, x1.y + x3.y);
      const float2 t1 = make_float2(x1.x - x3.x, x1.y - x3.y);
      s[i0]         = make_float2(s0.x + t0.x, s0.y + t0.y);
      s[i0 + q]     = make_float2(s1.x - t1.y, s1.y + t1.x);
      s[i0 + 2 * q] = make_float2(s0.x - t0.x, s0.y - t0.y);
      s[i0 + 3 * q] = make_float2(s1.x + t1.y, s1.y - t1.x);
    }
    __syncthreads();
  }
  const float inv = 1.0f / (float)MH;
  float2* orow = (float2*)(out + (size_t)b * NSAMP);
  for (int m = t; m < MH; m += 1024) {
    const float2 z = s[m];
    orow[m] = make_float2(z.x * inv, z.y * inv);
  }
}

// ---------------- dots: 64 batches x 128 atoms per block, split-bf16 MFMA, 3-buffer ----
// (R20-proven: 512 threads / 8 waves; wave w owns 32 batches x 32 atoms)
// partials[b][s][a] = sum_{k in slice s} res[b][k] * an[a][k]   (k < 32768 only)
__global__ __launch_bounds__(512) void dots_mfma_kernel(const unsigned short* __restrict__ resH,
                                                        const unsigned short* __restrict__ resL,
                                                        const unsigned short* __restrict__ anH,
                                                        const unsigned short* __restrict__ anL,
                                                        float* __restrict__ partials) {
  __shared__ char smem[147456];  // 3 x 48KB
  const int slice = blockIdx.x;  // 0..NSL-1, K = 512 per block, chunks of 64
  const int atile = blockIdx.y;  // 0..3, 128 atoms each
  const int t = threadIdx.x;
  const int w = t >> 6, l = t & 63;
  const int bh = w >> 2, aq = w & 3;        // wave's quadrant: 32 batches x 32 atoms
  const int kc0 = slice * 512;

  f32x4 acc00 = {0.f,0.f,0.f,0.f}, acc01 = acc00, acc10 = acc00, acc11 = acc00;

#define STAGE(cc, bb)                                                                     \
  {                                                                                       \
    const int kc = kc0 + (cc) * 64;                                                       \
    _Pragma("unroll")                                                                     \
    for (int j = 0; j < 6; ++j) {                                                         \
      const int u = w * 6 + j;                                                            \
      const unsigned short* gt = (u < 8) ? resH : (u < 16) ? resL : (u < 32) ? anH : anL; \
      const int base = (u < 8) ? 0 : (u < 16) ? 8192 : (u < 32) ? 16384 : 32768;          \
      const int usec = u - ((u < 8) ? 0 : (u < 16) ? 8 : (u < 32) ? 16 : 32);             \
      const int row0 = (u < 16) ? 0 : atile * BN2;                                        \
      const int rt = usec >> 1, kk = usec & 1;                                            \
      const unsigned short* g = gt + (size_t)(row0 + rt * 16 + (l & 15)) * KPS            \
                                + kc + kk * 32 + (l >> 4) * 8;                            \
      char* d = smem + (bb) * 49152 + base + usec * 1024 + l * 16;                        \
      __builtin_amdgcn_global_load_lds((const __attribute__((address_space(1))) void*)g,  \
                                       (__attribute__((address_space(3))) void*)d,        \
                                       16, 0, 0);                                        \
    }                                                                                     \
  }

#define COMPUTE(bb)                                                                      \
  {                                                                                       \
    const char* base = smem + (bb) * 49152;                                               \
    _Pragma("unroll")                                                                     \
    for (int kk = 0; kk < 2; ++kk) {                                                      \
      const bf16x8 aH0 = *(const bf16x8*)(base + ((bh * 2 + 0) * 2 + kk) * 1024 + l * 16);\
      const bf16x8 aH1 = *(const bf16x8*)(base + ((bh * 2 + 1) * 2 + kk) * 1024 + l * 16);\
      const bf16x8 aL0 = *(const bf16x8*)(base + 8192 + ((bh * 2 + 0) * 2 + kk) * 1024 + l * 16);\
      const bf16x8 aL1 = *(const bf16x8*)(base + 8192 + ((bh * 2 + 1) * 2 + kk) * 1024 + l * 16);\
      const bf16x8 bH0 = *(const bf16x8*)(base + 16384 + ((aq * 2 + 0) * 2 + kk) * 1024 + l * 16);\
      const bf16x8 bH1 = *(const bf16x8*)(base + 16384 + ((aq * 2 + 1) * 2 + kk) * 1024 + l * 16);\
      const bf16x8 bL0 = *(const bf16x8*)(base + 32768 + ((aq * 2 + 0) * 2 + kk) * 1024 + l * 16);\
      const bf16x8 bL1 = *(const bf16x8*)(base + 32768 + ((aq * 2 + 1) * 2 + kk) * 1024 + l * 16);\
      acc00 = __builtin_amdgcn_mfma_f32_16x16x32_bf16(aH0, bH0, acc00, 0, 0, 0);          \
      acc01 = __builtin_amdgcn_mfma_f32_16x16x32_bf16(aH0, bH1, acc01, 0, 0, 0);          \
      acc10 = __builtin_amdgcn_mfma_f32_16x16x32_bf16(aH1, bH0, acc10, 0, 0, 0);          \
      acc11 = __builtin_amdgcn_mfma_f32_16x16x32_bf16(aH1, bH1, acc11, 0, 0, 0);          \
      acc00 = __builtin_amdgcn_mfma_f32_16x16x32_bf16(aH0, bL0, acc00, 0, 0, 0);          \
      acc01 = __builtin_amdgcn_mfma_f32_16x16x32_bf16(aH0, bL1, acc01, 0, 0, 0);          \
      acc10 = __builtin_amdgcn_mfma_f32_16x16x32_bf16(aH1, bL0, acc10, 0, 0, 0);          \
      acc11 = __builtin_amdgcn_mfma_f32_16x16x32_bf16(aH1, bL1, acc11, 0, 0, 0);          \
      acc00 = __builtin_amdgcn_mfma_f32_16x16x32_bf16(aL0, bH0, acc00, 0, 0, 0);          \
      acc01 = __builtin_amdgcn_mfma_f32_16x16x32_bf16(aL0, bH1, acc01, 0, 0, 0);          \
      acc10 = __builtin_amdgcn_mfma_f32_16x16x32_bf16(aL1, bH0, acc10, 0, 0, 0);          \
      acc11 = __builtin_amdgcn_mfma_f32_16x16x32_bf16(aL1, bH1, acc11, 0, 0, 0);          \
    }                                                                                     \
  }

  STAGE(0, 0);
  STAGE(1, 1);
  #pragma unroll
  for (int c = 0; c < 8; ++c) {
    const int bf = c - (c / 3) * 3;   // c % 3
    if (c < 7) {
      asm volatile("s_waitcnt vmcnt(6)" ::: "memory");
    } else {
      asm volatile("s_waitcnt vmcnt(0)" ::: "memory");
    }
    __builtin_amdgcn_s_barrier();
    __builtin_amdgcn_sched_barrier(0);
    COMPUTE(bf);
    __builtin_amdgcn_sched_barrier(0);
    if (c < 6) {
      const int nb = c + 2;
      STAGE(nb, nb - (nb / 3) * 3);
    }
  }
#undef STAGE
#undef COMPUTE

  // D layout: row=(lane>>4)*4+e (batch), col=lane&15 (atom); partials [b][NSL][a]
  const int acol = atile * BN2 + aq * 32 + (l & 15);
  const size_t bstr = (size_t)NSL * NA;
  #pragma unroll
  for (int e = 0; e < 4; ++e) {
    const size_t r0 = (size_t)(bh * 32 + (l >> 4) * 4 + e);
    partials[r0 * bstr + (size_t)slice * NA + acol]             = acc00[e];
    partials[r0 * bstr + (size_t)slice * NA + acol + 16]        = acc01[e];
    partials[(r0 + 16) * bstr + (size_t)slice * NA + acol]      = acc10[e];
    partials[(r0 + 16) * bstr + (size_t)slice * NA + acol + 16] = acc11[e];
  }
}

// ---------------- fused per-batch: argmax (single scan) + full-row update ----------------
__global__ __launch_bounds__(1024) void argmax_update_kernel(const float* __restrict__ partials,
                                                             const float* __restrict__ atoms,
                                                             const float* __restrict__ rnorm,
                                                             const float* __restrict__ anv,
                                                             unsigned short* __restrict__ resH,
                                                             unsigned short* __restrict__ resL,
                                                             const float* __restrict__ res0,
                                                             float* __restrict__ rec,
                                                             float* __restrict__ out2,
                                                             int final_out) {
  const int b = blockIdx.x;
  const int t = threadIdx.x;
  unsigned short* hrow = resH + (size_t)b * KPS;
  unsigned short* lrow = resL + (size_t)b * KPS;

  // ---- phase 1: argmax ----
  __shared__ float sv[1024];
  __shared__ int si[1024];
  {
    const int a = t & 511, half = t >> 9;
    const float* pb = partials + (size_t)b * NSL * NA + (size_t)half * 32 * NA;
    float d = 0.f;
    #pragma unroll 16
    for (int s = 0; s < 32; ++s) d += pb[(size_t)s * NA + a];
    sv[t] = d; __syncthreads();
    if (t < 512) {
      float dd = sv[t] + sv[t + 512];
      const float rv = bf2f(hrow[32768]) + bf2f(lrow[32768]);   // k=32768 rank-1 term
      dd = fmaf(rv, anv[t], dd);
      sv[t] = dd; si[t] = t;
    }
    __syncthreads();
    for (int st = 256; st > 0; st >>= 1) {
      if (t < st) {
        const float v2 = sv[t + st]; const int i2 = si[t + st];
        if (v2 > sv[t] || (v2 == sv[t] && i2 < si[t])) { sv[t] = v2; si[t] = i2; }
      }
      __syncthreads();
    }
  }
  const int idx = si[0];

  // ---- phase 2: full-row update with 1024 threads ----
  const float rn = rnorm[idx];
  const float* arow = atoms + (size_t)idx * LFREQ;
  const float* r0row = res0 + (size_t)b * RSTR;
  float* recrow = rec + (size_t)b * RSTR;
  float* orow = out2 + (size_t)b * LFREQ;
  for (int c = t; c < NCH; c += 1024) {
    const int k0 = c * 8;
    if (k0 + 8 <= LFREQ) {
      const u16x8 hv0 = *(const u16x8*)(hrow + k0);
      const u16x8 lv0 = *(const u16x8*)(lrow + k0);
      float av[8];
      #pragma unroll
      for (int e = 0; e < 4; ++e) {
        const float2 p = *(const float2*)(arow + k0 + 2 * e);
        av[2 * e] = p.x; av[2 * e + 1] = p.y;
      }
      float nv[8];
      u16x8 hv, lv;
      #pragma unroll
      for (int e = 0; e < 8; ++e) {
        const float r = bf2f(hv0[e]) + bf2f(lv0[e]);
        const float bx = av[e] * rn * r;
        nv[e] = r - bx;
        const unsigned short h = f2bf(nv[e]);
        hv[e] = h;
        lv[e] = f2bf(nv[e] - bf2f(h));
      }
      *(u16x8*)(hrow + k0) = hv;
      *(u16x8*)(lrow + k0) = lv;
      if (final_out) {
        #pragma unroll
        for (int e = 0; e < 2; ++e) {
          const float4 r0 = *(const float4*)(r0row + k0 + 4 * e);
          *(float4*)(orow + k0 + 4 * e) = make_float4(nv[4*e], nv[4*e+1], nv[4*e+2], nv[4*e+3]);
          *(float4*)(recrow + k0 + 4 * e) = make_float4(r0.x - nv[4*e], r0.y - nv[4*e+1],
                                                       r0.z - nv[4*e+2], r0.w - nv[4*e+3]);
        }
      }
    } else {
      for (int e = 0; e < 8; ++e) {
        const int k = k0 + e;
        if (k < LFREQ) {
          const float r = bf2f(hrow[k]) + bf2f(lrow[k]);
          const float bx = arow[k] * rn * r;
          const float nx = r - bx;
          const unsigned short h = f2bf(nx);
          hrow[k] = h;
          lrow[k] = f2bf(nx - bf2f(h));
          if (final_out) {
            orow[k] = nx;
            recrow[k] = r0row[k] - nx;
          }
        }
      }
    }
  }
}

extern "C" void kernel_launch(void* const* d_in, const int* in_sizes, int n_in,
                              void* d_out, int out_size, void* d_ws, size_t ws_size,
                              hipStream_t stream) {
  const float* x = (const float*)d_in[0];      // (64,1,32768)
  const float* atoms = (const float*)d_in[1];  // (1,512,32770)
  float* out = (float*)d_out;

  float* res0 = (float*)d_ws;                            // 64*32772 f32 (initial rfft)
  float* rec = res0 + (size_t)NB * RSTR;                 // 64*32772 f32 (final only)
  float* rnorm = rec + (size_t)NB * RSTR;                // 512
  float* anv = rnorm + NA;                               // 512
  float* partials = anv + NA;                            // 64*64*512 f32  [b][s][a]
  unsigned short* resH = (unsigned short*)(partials + (size_t)NB * NSL * NA);
  unsigned short* resL = resH + (size_t)NB * KPS;
  unsigned short* anH  = resL + (size_t)NB * KPS;
  unsigned short* anL  = anH + (size_t)NA * KPS;

  prologue_kernel<<<64 + NA, 1024, MH * sizeof(float2), stream>>>(x, res0, resH, resL,
                                                                  atoms, rnorm, anv,
                                                                  anH, anL);

  float* res_out = out + (size_t)NB * NSAMP;
  for (int it = 0; it < NITER; ++it) {
    dots_mfma_kernel<<<dim3(NSL, 4), 512, 0, stream>>>(resH, resL, anH, anL, partials);
    argmax_update_kernel<<<NB, 1024, 0, stream>>>(partials, atoms, rnorm, anv,
                                                  resH, resL, res0, rec, res_out,
                                                  (it == NITER - 1) ? 1 : 0);
  }

  fft_inv_kernel<<<NB, 1024, MH * sizeof(float2), stream>>>(rec, out);
}